// Round 8
// baseline (1436.294 us; speedup 1.0000x reference)
//
#include <hip/hip_runtime.h>

// 4-layer 5-point cross-stencil CNN, implicit GEMM on MFMA (MI355X gfx950).
// Round 13 = round 12 resubmitted (bench infra failed twice; no data).
// Round 12: gmid -> persistent 4-tile j-walk with T14 reg-staged prefetch.
//   Theory: per-block serial stage-drain (46KB from L3, ~4k cy) convoys the
//   3 resident blocks (identical barrier-gated phases) -> CU idles; raw MFMA
//   pipe occupancy only ~8% despite MfmaUtil 28%. r9 (-50us) shortened this
//   drain; this round hides it: block walks 4 j-tiles, tile t+1 is loaded to
//   registers (12 x f16x8/thread, issued 6 pre-kloop + 6 mid-epilogue,
//   sched_barrier-pinned) during tile t's compute, flushed to LDS after the
//   end-of-tile barrier. LDS image/swizzle/lda/fixup byte-equivalent to r9.
//   Grid 4x32x8 = 1024 blocks, LDS 46KB, 3 blocks/CU unchanged.
//   VGPR budget: acc64 + frags32 + vst24(live) + misc ~= 146 < 170 cap.
//   Spill signature to watch (r7): FETCH>90MB / WRITE>140MB -> revert.
//   g1/g4/prep byte-identical to round 11.
// MFMA 16x16x32_f16 layouts (verified round 3):
//   A[m=lane&15][k=quad*8+j], B[n=lane&15][k=quad*8+j], C: col=lane&15,
//   row=quad*4+reg.   Taps: 0=c,1=up,2=down,3=left,4=right.

#define BB   8
#define HH   256
#define WW   256

typedef _Float16 f16x8 __attribute__((ext_vector_type(8)));
typedef float    f32x4 __attribute__((ext_vector_type(4)));

// K-major fp16 weight tables (rewritten every launch by prep).
__device__ _Float16 W1g[128 * 32];       // [oc][k], k=tap*6+ic, 30..31 = 0
__device__ _Float16 W2g[20 * 128 * 32];  // [ks=tap*4+kc][oc][icb]
__device__ _Float16 W3g[20 * 128 * 32];
__device__ _Float16 W4g[5 * 16 * 128];   // [tap][oc(pad16)][ic]

__global__ void prep(const float* __restrict__ w1, const float* __restrict__ w2,
                     const float* __restrict__ w3, const float* __restrict__ w4)
{
    int idx = blockIdx.x * 256 + threadIdx.x;
    if (idx < 81920) {                                  // W2g
        int icb = idx & 31, oc = (idx >> 5) & 127, ks = idx >> 12;
        int tap = ks >> 2, ic = (ks & 3) * 32 + icb;
        W2g[idx] = (_Float16)w2[(oc * 128 + ic) * 5 + tap];
    } else if (idx < 163840) {                          // W3g
        int k = idx - 81920;
        int icb = k & 31, oc = (k >> 5) & 127, ks = k >> 12;
        int tap = ks >> 2, ic = (ks & 3) * 32 + icb;
        W3g[k] = (_Float16)w3[(oc * 128 + ic) * 5 + tap];
    } else if (idx < 174080) {                          // W4g
        int k = idx - 163840;
        int t = k / 2048, oc = (k >> 7) & 15, ic = k & 127;
        W4g[k] = (_Float16)((oc < 6) ? w4[(oc * 128 + ic) * 5 + t] : 0.f);
    } else if (idx < 178176) {                          // W1g
        int k = idx - 174080;
        int kk = k & 31, oc = k >> 5;
        float v = 0.f;
        if (kk < 30) {
            int tap = (kk * 43) >> 8;                   // kk/6 for kk<30
            int ic = kk - 6 * tap;
            v = w1[(oc * 6 + ic) * 5 + tap];
        }
        W1g[k] = (_Float16)v;
    }
}

// ---------------- L1: MFMA, K=32 (tap*6+ic, padded). NCHW fp32 -> NHWC fp16.
// Staging planes k=2*it+HALF: HALF wave-uniform -> tap/ic/di/dj compile-time.
template<int HALF, bool EDGE>
__device__ __forceinline__ void g1_stage(const float* __restrict__ xb,
                                         _Float16* __restrict__ Ap,
                                         int px, int gi0, int gj0)
{
#pragma unroll
    for (int it = 0; it < 15; ++it) {
        const int k = 2 * it + HALF;                    // compile-time
        const int tap = k / 6, ic = k - 6 * tap;
        const int DI = (tap == 1) ? -1 : ((tap == 2) ? 1 : 0);
        const int DJ = (tap == 3) ? -1 : ((tap == 4) ? 1 : 0);
        const float* sp = xb + ic * 65536 + DI * 256 + DJ;
        float v;
        if (EDGE) {
            const int gi = gi0 + DI, gj = gj0 + DJ;
            v = ((unsigned)gi < 256u && (unsigned)gj < 256u) ? *sp : 0.f;
        } else {
            v = *sp;
        }
        Ap[px * 40 + k] = (_Float16)v;
    }
    Ap[px * 40 + 30 + HALF] = (_Float16)0.f;            // K-pad 30/31
}

__global__ __launch_bounds__(256, 3) void g1(
    const float* __restrict__ x, const float* __restrict__ bias,
    _Float16* __restrict__ outp)
{
    __shared__ _Float16 Ap[128 * 40];
    const int tid = threadIdx.x;
    const int j0 = blockIdx.x * 16, i0 = blockIdx.y * 8, b = blockIdx.z;
    const int px = tid & 127, half = tid >> 7;
    const int pr = px >> 4, pp = px & 15;
    const bool edge = (blockIdx.y == 0) | (blockIdx.y == 31) |
                      (blockIdx.x == 0) | (blockIdx.x == 15);
    const int gi0 = i0 + pr, gj0 = j0 + pp;
    const float* xb = x + (size_t)b * 6 * 65536 + gi0 * 256 + gj0;

    if (edge) {
        if (half == 0) g1_stage<0, true >(xb, Ap, px, gi0, gj0);
        else           g1_stage<1, true >(xb, Ap, px, gi0, gj0);
    } else {
        if (half == 0) g1_stage<0, false>(xb, Ap, px, gi0, gj0);
        else           g1_stage<1, false>(xb, Ap, px, gi0, gj0);
    }
    __syncthreads();

    const int lane = tid & 63, w = tid >> 6, l16 = lane & 15, quad = lane >> 4;
    f32x4 acc[2][8] = {};
    f16x8 a0 = *(const f16x8*)&Ap[((2 * w + 0) * 16 + l16) * 40 + quad * 8];
    f16x8 a1 = *(const f16x8*)&Ap[((2 * w + 1) * 16 + l16) * 40 + quad * 8];
#pragma unroll
    for (int nf = 0; nf < 8; ++nf) {
        f16x8 bf = *(const f16x8*)&W1g[(nf * 16 + l16) * 32 + quad * 8];
        acc[0][nf] = __builtin_amdgcn_mfma_f32_16x16x32_f16(a0, bf, acc[0][nf], 0, 0, 0);
        acc[1][nf] = __builtin_amdgcn_mfma_f32_16x16x32_f16(a1, bf, acc[1][nf], 0, 0, 0);
    }
#pragma unroll
    for (int mf = 0; mf < 2; ++mf) {
        const size_t rowb = ((size_t)b * 256 + i0 + 2 * w + mf) * 256 + j0;
#pragma unroll
        for (int nf = 0; nf < 8; ++nf) {
            const float bv = bias[nf * 16 + l16];
#pragma unroll
            for (int r = 0; r < 4; ++r)
                outp[(rowb + quad * 4 + r) * 128 + nf * 16 + l16] =
                    (_Float16)fmaxf(acc[mf][nf][r] + bv, 0.f);
        }
    }
}

// ---------------- middle layers: persistent 4-tile j-walk -------------------
// Block = (jh, band, b): walks tiles j0 = jh*64 + t*16, t=0..3, rows i0..i0+7.
// LDS [180 sites][128] linear, image identical to round 9. Tile t+1 staged to
// registers during tile t's kloop/epilogue, flushed to LDS after barrier.
template<int LAYER>
__global__ __launch_bounds__(256, 3) void gmid(
    const _Float16* __restrict__ in, const float* __restrict__ bias,
    _Float16* __restrict__ outp)
{
    const _Float16* wt = (LAYER == 2) ? W2g : W3g;
    __shared__ __align__(16) _Float16 Al[180 * 128];    // 46080 B, linear
    const int tid = threadIdx.x;
    const int lane = tid & 63, w = tid >> 6;
    const int jh = blockIdx.x, band = blockIdx.y, b = blockIdx.z;
    const int i0 = band * 8;
    const bool top = (band == 0), bot = (band == 31);

    // chunk map: id = tid + 256k (k<12; k=11 only tid<64); site s = id>>4,
    // stored chunk c = id&15 holds global chunk c^(s&7). LDS half-addr
    // s*128 + c*8 — identical image to the r9 gload_lds layout.
    auto src_off = [&](int k, int j0t) -> unsigned {
        const int id = tid + 256 * k, s = id >> 4, c = id & 15;
        const int r = (s * 114) >> 11, p = s - 18 * r;   // s/18, s%18
        int gi = i0 - 1 + r; gi = gi < 0 ? 0 : (gi > 255 ? 255 : gi);
        int gj = j0t - 1 + p; gj = gj < 0 ? 0 : (gj > 255 ? 255 : gj);
        return (unsigned)((((b * 256 + gi) * 256 + gj) * 128) + ((c ^ (s & 7)) << 3));
    };
    auto lds_off = [&](int k) -> int {
        const int id = tid + 256 * k, s = id >> 4, c = id & 15;
        return s * 128 + c * 8;
    };

    f16x8 vst[12];
#define ISSUE(k, j0t) vst[k] = *(const f16x8*)&in[src_off(k, j0t)]
#define FLUSH(k)      *(f16x8*)&Al[lds_off(k)] = vst[k]

    auto fixup = [&](bool ftop, bool fbot, bool fl, bool fr) {
#pragma unroll
        for (int pass = 0; pass < 2; ++pass) {
            const int gidx = (tid >> 3) + 32 * pass, c = tid & 7;
            int sid = -1;
            if (gidx < 18)      { if (ftop) sid = gidx; }              // r=0
            else if (gidx < 36) { if (fbot) sid = 162 + gidx - 18; }   // r=9
            else if (gidx < 46) { if (fl)   sid = (gidx - 36) * 18; }         // p=0
            else if (gidx < 56) { if (fr)   sid = (gidx - 46) * 18 + 17; }    // p=17
            if (sid >= 0) {
                const f16x8 z = {};
                *(f16x8*)(Al + sid * 128 + c * 16)     = z;
                *(f16x8*)(Al + sid * 128 + c * 16 + 8) = z;
            }
        }
    };

    const int l16 = lane & 15, quad = lane >> 4;
    const int mg = w & 1, ng = w >> 1;
    const int r0 = mg * 4, n0 = ng * 64;
    const _Float16* wb = wt + (size_t)(n0 + l16) * 32 + quad * 8;
    const int DR[5] = {1, 0, 2, 1, 1}, DP[5] = {1, 1, 1, 0, 2};
    float bv[4];
#pragma unroll
    for (int nf = 0; nf < 4; ++nf) bv[nf] = bias[n0 + nf * 16 + l16];

    auto lda = [&](int ks, int r) -> f16x8 {
        const int tap = ks >> 2, kc = ks & 3;
        const int s = (DR[tap] + r0 + r) * 18 + DP[tap] + l16;
        const int ch = (kc * 4 + quad) ^ (s & 7);
        return *(const f16x8*)&Al[s * 128 + ch * 8];
    };

    // ---- prologue: stage tile 0 (not overlapped)
    {
        const int j00 = jh * 64;
#pragma unroll
        for (int k = 0; k < 11; ++k) ISSUE(k, j00);
        if (tid < 64) ISSUE(11, j00);
#pragma unroll
        for (int k = 0; k < 11; ++k) FLUSH(k);
        if (tid < 64) FLUSH(11);
    }
    __syncthreads();
    {
        const bool fl = (jh == 0);
        if (top | bot | fl) { fixup(top, bot, fl, false); __syncthreads(); }
    }

#pragma unroll 1
    for (int t = 0; t < 4; ++t) {
        const int j0 = jh * 64 + t * 16;
        const int j0n = j0 + 16;

        if (t < 3) {                       // stage issue, first half
#pragma unroll
            for (int k = 0; k < 6; ++k) ISSUE(k, j0n);
            __builtin_amdgcn_sched_barrier(0);
        }

        f32x4 acc[4][4] = {};
        f16x8 bc[4], bn[4], ac[4], an[4];
#pragma unroll
        for (int nf = 0; nf < 4; ++nf) bc[nf] = *(const f16x8*)(wb + nf * 512);
#pragma unroll
        for (int r = 0; r < 4; ++r) ac[r] = lda(0, r);

#pragma unroll
        for (int ks = 0; ks < 20; ++ks) {
            if (ks < 19) {
#pragma unroll
                for (int nf = 0; nf < 4; ++nf)
                    bn[nf] = *(const f16x8*)(wb + (size_t)(ks + 1) * 4096 + nf * 512);
#pragma unroll
                for (int r = 0; r < 4; ++r) an[r] = lda(ks + 1, r);
            }
            __builtin_amdgcn_s_setprio(1);
#pragma unroll
            for (int r = 0; r < 4; ++r)
#pragma unroll
                for (int nf = 0; nf < 4; ++nf)
                    acc[r][nf] = __builtin_amdgcn_mfma_f32_16x16x32_f16(
                        ac[r], bc[nf], acc[r][nf], 0, 0, 0);
            __builtin_amdgcn_s_setprio(0);
#pragma unroll
            for (int nf = 0; nf < 4; ++nf) bc[nf] = bn[nf];
#pragma unroll
            for (int r = 0; r < 4; ++r) ac[r] = an[r];
        }

        // epilogue A: rows 0,1
#pragma unroll
        for (int r = 0; r < 2; ++r) {
            const size_t rowb = ((size_t)b * 256 + i0 + r0 + r) * 256 + j0;
#pragma unroll
            for (int nf = 0; nf < 4; ++nf)
#pragma unroll
                for (int vi = 0; vi < 4; ++vi)
                    outp[(rowb + quad * 4 + vi) * 128 + n0 + nf * 16 + l16] =
                        (_Float16)fmaxf(acc[r][nf][vi] + bv[nf], 0.f);
        }
        if (t < 3) {                       // stage issue, second half
#pragma unroll
            for (int k = 6; k < 11; ++k) ISSUE(k, j0n);
            if (tid < 64) ISSUE(11, j0n);
            __builtin_amdgcn_sched_barrier(0);
        }
        // epilogue B: rows 2,3
#pragma unroll
        for (int r = 2; r < 4; ++r) {
            const size_t rowb = ((size_t)b * 256 + i0 + r0 + r) * 256 + j0;
#pragma unroll
            for (int nf = 0; nf < 4; ++nf)
#pragma unroll
                for (int vi = 0; vi < 4; ++vi)
                    outp[(rowb + quad * 4 + vi) * 128 + n0 + nf * 16 + l16] =
                        (_Float16)fmaxf(acc[r][nf][vi] + bv[nf], 0.f);
        }

        if (t < 3) {
            __syncthreads();               // all waves done reading Al
#pragma unroll
            for (int k = 0; k < 11; ++k) FLUSH(k);
            if (tid < 64) FLUSH(11);
            __syncthreads();               // new tile visible
            const bool fr = (jh == 3) && (t + 1 == 3);
            if (top | bot | fr) { fixup(top, bot, false, fr); __syncthreads(); }
        }
    }
#undef ISSUE
#undef FLUSH
}

// ---------------- L4: 128 -> 6 (pad 16), gmid-style tiles + gload_lds -------
// 8-row x 16-px tile (grid 16x32x8). Staging/fixup identical to round-9 gmid.
// M = 128 px (8 frags of 16), N = 16 (6 oc + pad), K = 640.
// Wave w computes M-frags {2w, 2w+1} (rows 2w, 2w+1). 40 MFMA/wave.
// 1-deep prefetch of (bf, af0, af1) across the k-loop.
__global__ __launch_bounds__(256, 3) void g4(
    const _Float16* __restrict__ in, const float* __restrict__ bias,
    float* __restrict__ outp)
{
    __shared__ __align__(16) _Float16 Al[180 * 128];    // 46080 B, linear
    const int tid = threadIdx.x;
    const int lane = tid & 63, w = tid >> 6;
    const int j0 = blockIdx.x * 16, i0 = blockIdx.y * 8, b = blockIdx.z;
    const bool top = (blockIdx.y == 0), bot = (blockIdx.y == 31);
    const bool left = (blockIdx.x == 0), right = (blockIdx.x == 15);

    {
        const int pxl = lane & 15;
#pragma unroll
        for (int k = 0; k < 12; ++k) {
            const int m = w + 4 * k;
            if (m < 45) {
                const int s = 4 * m + (lane >> 4);
                const int r = (s * 114) >> 11;          // s/18 for s<288
                const int p = s - 18 * r;
                int gi = i0 - 1 + r; gi = gi < 0 ? 0 : (gi > 255 ? 255 : gi);
                int gj = j0 - 1 + p; gj = gj < 0 ? 0 : (gj > 255 ? 255 : gj);
                const _Float16* src = in + (((size_t)(b * 256 + gi)) * 256 + gj) * 128
                                         + ((pxl ^ (s & 7)) << 3);
                __builtin_amdgcn_global_load_lds(
                    (const __attribute__((address_space(1))) void*)src,
                    (__attribute__((address_space(3))) void*)(Al + m * 512),
                    16, 0, 0);
            }
        }
    }
    __syncthreads();
    if (top | bot | left | right) {                     // zero clamp-loaded halo
#pragma unroll
        for (int pass = 0; pass < 2; ++pass) {
            const int gidx = (tid >> 3) + 32 * pass, c = tid & 7;
            int sid = -1;
            if (gidx < 18)      { if (top)   sid = gidx; }             // r=0
            else if (gidx < 36) { if (bot)   sid = 162 + gidx - 18; }  // r=9
            else if (gidx < 46) { if (left)  sid = (gidx - 36) * 18; }        // p=0
            else if (gidx < 56) { if (right) sid = (gidx - 46) * 18 + 17; }   // p=17
            if (sid >= 0) {
                const f16x8 z = {};
                *(f16x8*)(Al + sid * 128 + c * 16)     = z;
                *(f16x8*)(Al + sid * 128 + c * 16 + 8) = z;
            }
        }
        __syncthreads();
    }

    const int l16 = lane & 15, quad = lane >> 4;
    const int DR[5] = {1, 0, 2, 1, 1}, DP[5] = {1, 1, 1, 0, 2};

    auto lda = [&](int ks, int row) -> f16x8 {
        const int tap = ks >> 2, kc = ks & 3;
        const int s = (DR[tap] + row) * 18 + DP[tap] + l16;
        const int ch = (kc * 4 + quad) ^ (s & 7);
        return *(const f16x8*)&Al[s * 128 + ch * 8];
    };
    auto ldb = [&](int ks) -> f16x8 {
        const int tap = ks >> 2, kc = ks & 3;
        return *(const f16x8*)&W4g[(size_t)(tap * 16 + l16) * 128 + kc * 32 + quad * 8];
    };

    f32x4 acc[2] = {};
    f16x8 bfc = ldb(0), bfn;
    f16x8 afc0 = lda(0, 2 * w), afc1 = lda(0, 2 * w + 1), afn0, afn1;
#pragma unroll
    for (int ks = 0; ks < 20; ++ks) {
        if (ks < 19) {
            bfn  = ldb(ks + 1);
            afn0 = lda(ks + 1, 2 * w);
            afn1 = lda(ks + 1, 2 * w + 1);
        }
        __builtin_amdgcn_s_setprio(1);
        acc[0] = __builtin_amdgcn_mfma_f32_16x16x32_f16(afc0, bfc, acc[0], 0, 0, 0);
        acc[1] = __builtin_amdgcn_mfma_f32_16x16x32_f16(afc1, bfc, acc[1], 0, 0, 0);
        __builtin_amdgcn_s_setprio(0);
        bfc = bfn; afc0 = afn0; afc1 = afn1;
    }

    if (l16 < 6) {
        const float bb = bias[l16];
#pragma unroll
        for (int f = 0; f < 2; ++f) {
            const int i = i0 + 2 * w + f;
#pragma unroll
            for (int vi = 0; vi < 4; ++vi) {
                int jj = j0 + quad * 4 + vi;
                outp[(((size_t)b * 6 + l16) << 16) + i * 256 + jj] = acc[f][vi] + bb;
            }
        }
    }
}

extern "C" void kernel_launch(void* const* d_in, const int* in_sizes, int n_in,
                              void* d_out, int out_size, void* d_ws, size_t ws_size,
                              hipStream_t stream) {
    const float* x  = (const float*)d_in[0];
    const float* w1 = (const float*)d_in[1];
    const float* b1 = (const float*)d_in[2];
    const float* w2 = (const float*)d_in[3];
    const float* b2 = (const float*)d_in[4];
    const float* w3 = (const float*)d_in[5];
    const float* b3 = (const float*)d_in[6];
    const float* w4 = (const float*)d_in[7];
    const float* b4 = (const float*)d_in[8];
    float* out = (float*)d_out;

    const size_t act = (size_t)BB * HH * WW * 128;
    _Float16* A1 = (_Float16*)d_ws;
    _Float16* A2 = A1 + act;                    // exactly 268435456 B total

    prep<<<696, 256, 0, stream>>>(w1, w2, w3, w4);
    dim3 blk(256, 1, 1);
    dim3 gm(16, 32, 8);                         // 16-px x 8-row tiles
    g1<<<gm, blk, 0, stream>>>(x, b1, A1);
    gmid<2><<<dim3(4, 32, 8), blk, 0, stream>>>(A1, b2, A2);
    gmid<3><<<dim3(4, 32, 8), blk, 0, stream>>>(A2, b3, A1);
    g4<<<gm, blk, 0, stream>>>(A1, b4, out);
}

// Round 9
// 1024.954 us; speedup vs baseline: 1.4013x; 1.4013x over previous
//
#include <hip/hip_runtime.h>

// 4-layer 5-point cross-stencil CNN, implicit GEMM on MFMA (MI355X gfx950).
// Round 14: r11 base + gmid batch-walk(2) with ZERO-REGISTER staging overlap.
//   r13 post-mortem: reg-staged prefetch spilled again (VGPR pinned 84;
//   FETCH 645MB/WRITE 564MB, 654us). Register pipelining is closed at
//   3 blocks/CU. This round: same overlap mechanism via global_load_lds
//   (loads live in the vmcnt queue, not VGPRs). Block walks b0 and b0+4
//   (j0/band fixed -> fixup conditions per-block constant). After k-loop:
//   lgkmcnt(0)+barrier (all waves past their last ds_read) -> stage next
//   tile into the SAME LDS buffer -> epilogue (registers/global only)
//   covers the drain -> vmcnt(0)+barrier -> fixup. Grid (16,32,4).
//   Spill tripwire: FETCH>90MB or WRITE>140MB => revert.
//   g1/g4/prep byte-identical to round 11 (384us best).
// MFMA 16x16x32_f16 layouts (verified round 3):
//   A[m=lane&15][k=quad*8+j], B[n=lane&15][k=quad*8+j], C: col=lane&15,
//   row=quad*4+reg.   Taps: 0=c,1=up,2=down,3=left,4=right.

#define BB   8
#define HH   256
#define WW   256

typedef _Float16 f16x8 __attribute__((ext_vector_type(8)));
typedef float    f32x4 __attribute__((ext_vector_type(4)));

// K-major fp16 weight tables (rewritten every launch by prep).
__device__ _Float16 W1g[128 * 32];       // [oc][k], k=tap*6+ic, 30..31 = 0
__device__ _Float16 W2g[20 * 128 * 32];  // [ks=tap*4+kc][oc][icb]
__device__ _Float16 W3g[20 * 128 * 32];
__device__ _Float16 W4g[5 * 16 * 128];   // [tap][oc(pad16)][ic]

__global__ void prep(const float* __restrict__ w1, const float* __restrict__ w2,
                     const float* __restrict__ w3, const float* __restrict__ w4)
{
    int idx = blockIdx.x * 256 + threadIdx.x;
    if (idx < 81920) {                                  // W2g
        int icb = idx & 31, oc = (idx >> 5) & 127, ks = idx >> 12;
        int tap = ks >> 2, ic = (ks & 3) * 32 + icb;
        W2g[idx] = (_Float16)w2[(oc * 128 + ic) * 5 + tap];
    } else if (idx < 163840) {                          // W3g
        int k = idx - 81920;
        int icb = k & 31, oc = (k >> 5) & 127, ks = k >> 12;
        int tap = ks >> 2, ic = (ks & 3) * 32 + icb;
        W3g[k] = (_Float16)w3[(oc * 128 + ic) * 5 + tap];
    } else if (idx < 174080) {                          // W4g
        int k = idx - 163840;
        int t = k / 2048, oc = (k >> 7) & 15, ic = k & 127;
        W4g[k] = (_Float16)((oc < 6) ? w4[(oc * 128 + ic) * 5 + t] : 0.f);
    } else if (idx < 178176) {                          // W1g
        int k = idx - 174080;
        int kk = k & 31, oc = k >> 5;
        float v = 0.f;
        if (kk < 30) {
            int tap = (kk * 43) >> 8;                   // kk/6 for kk<30
            int ic = kk - 6 * tap;
            v = w1[(oc * 6 + ic) * 5 + tap];
        }
        W1g[k] = (_Float16)v;
    }
}

// ---------------- L1: MFMA, K=32 (tap*6+ic, padded). NCHW fp32 -> NHWC fp16.
// Staging planes k=2*it+HALF: HALF wave-uniform -> tap/ic/di/dj compile-time.
template<int HALF, bool EDGE>
__device__ __forceinline__ void g1_stage(const float* __restrict__ xb,
                                         _Float16* __restrict__ Ap,
                                         int px, int gi0, int gj0)
{
#pragma unroll
    for (int it = 0; it < 15; ++it) {
        const int k = 2 * it + HALF;                    // compile-time
        const int tap = k / 6, ic = k - 6 * tap;
        const int DI = (tap == 1) ? -1 : ((tap == 2) ? 1 : 0);
        const int DJ = (tap == 3) ? -1 : ((tap == 4) ? 1 : 0);
        const float* sp = xb + ic * 65536 + DI * 256 + DJ;
        float v;
        if (EDGE) {
            const int gi = gi0 + DI, gj = gj0 + DJ;
            v = ((unsigned)gi < 256u && (unsigned)gj < 256u) ? *sp : 0.f;
        } else {
            v = *sp;
        }
        Ap[px * 40 + k] = (_Float16)v;
    }
    Ap[px * 40 + 30 + HALF] = (_Float16)0.f;            // K-pad 30/31
}

__global__ __launch_bounds__(256, 3) void g1(
    const float* __restrict__ x, const float* __restrict__ bias,
    _Float16* __restrict__ outp)
{
    __shared__ _Float16 Ap[128 * 40];
    const int tid = threadIdx.x;
    const int j0 = blockIdx.x * 16, i0 = blockIdx.y * 8, b = blockIdx.z;
    const int px = tid & 127, half = tid >> 7;
    const int pr = px >> 4, pp = px & 15;
    const bool edge = (blockIdx.y == 0) | (blockIdx.y == 31) |
                      (blockIdx.x == 0) | (blockIdx.x == 15);
    const int gi0 = i0 + pr, gj0 = j0 + pp;
    const float* xb = x + (size_t)b * 6 * 65536 + gi0 * 256 + gj0;

    if (edge) {
        if (half == 0) g1_stage<0, true >(xb, Ap, px, gi0, gj0);
        else           g1_stage<1, true >(xb, Ap, px, gi0, gj0);
    } else {
        if (half == 0) g1_stage<0, false>(xb, Ap, px, gi0, gj0);
        else           g1_stage<1, false>(xb, Ap, px, gi0, gj0);
    }
    __syncthreads();

    const int lane = tid & 63, w = tid >> 6, l16 = lane & 15, quad = lane >> 4;
    f32x4 acc[2][8] = {};
    f16x8 a0 = *(const f16x8*)&Ap[((2 * w + 0) * 16 + l16) * 40 + quad * 8];
    f16x8 a1 = *(const f16x8*)&Ap[((2 * w + 1) * 16 + l16) * 40 + quad * 8];
#pragma unroll
    for (int nf = 0; nf < 8; ++nf) {
        f16x8 bf = *(const f16x8*)&W1g[(nf * 16 + l16) * 32 + quad * 8];
        acc[0][nf] = __builtin_amdgcn_mfma_f32_16x16x32_f16(a0, bf, acc[0][nf], 0, 0, 0);
        acc[1][nf] = __builtin_amdgcn_mfma_f32_16x16x32_f16(a1, bf, acc[1][nf], 0, 0, 0);
    }
#pragma unroll
    for (int mf = 0; mf < 2; ++mf) {
        const size_t rowb = ((size_t)b * 256 + i0 + 2 * w + mf) * 256 + j0;
#pragma unroll
        for (int nf = 0; nf < 8; ++nf) {
            const float bv = bias[nf * 16 + l16];
#pragma unroll
            for (int r = 0; r < 4; ++r)
                outp[(rowb + quad * 4 + r) * 128 + nf * 16 + l16] =
                    (_Float16)fmaxf(acc[mf][nf][r] + bv, 0.f);
        }
    }
}

// ---------------- middle layers: M=128 (8 rows x 16 px), N=128, K=640 -------
// 2x2 wave grid: wave(mg,ng) owns rows r0..r0+3 and oc n0..n0+63.
// Batch-walk: block handles b0 and b0+4 (j0/band fixed). Tile 2's staging is
// issued after {lgkmcnt(0); barrier} post-k-loop and drains under tile 1's
// epilogue (global_load_lds: no VGPRs). 1-deep A/B prefetch in the k-loop.
template<int LAYER>
__global__ __launch_bounds__(256, 3) void gmid(
    const _Float16* __restrict__ in, const float* __restrict__ bias,
    _Float16* __restrict__ outp)
{
    const _Float16* wt = (LAYER == 2) ? W2g : W3g;
    __shared__ __align__(16) _Float16 Al[180 * 128];    // 46080 B, linear
    const int tid = threadIdx.x;
    const int lane = tid & 63, w = tid >> 6;
    const int j0 = blockIdx.x * 16, i0 = blockIdx.y * 8, b0 = blockIdx.z;
    const bool top = (blockIdx.y == 0), bot = (blockIdx.y == 31);
    const bool left = (blockIdx.x == 0), right = (blockIdx.x == 15);
    const bool edge = top | bot | left | right;
    const int pxl = lane & 15;

    // staging: instr m stages sites 4m..4m+3 (1024 B linear LDS); lane l ->
    // site s=4m+(l>>4); stored chunk (l&15) := global chunk (l&15)^(s&7).
    auto stage = [&](int bb) {
#pragma unroll
        for (int k = 0; k < 12; ++k) {
            const int m = w + 4 * k;
            if (m < 45) {
                const int s = 4 * m + (lane >> 4);
                const int r = (s * 114) >> 11;          // s/18 for s<288
                const int p = s - 18 * r;
                int gi = i0 - 1 + r; gi = gi < 0 ? 0 : (gi > 255 ? 255 : gi);
                int gj = j0 - 1 + p; gj = gj < 0 ? 0 : (gj > 255 ? 255 : gj);
                const _Float16* src = in + (((size_t)(bb * 256 + gi)) * 256 + gj) * 128
                                         + ((pxl ^ (s & 7)) << 3);
                __builtin_amdgcn_global_load_lds(
                    (const __attribute__((address_space(1))) void*)src,
                    (__attribute__((address_space(3))) void*)(Al + m * 512),
                    16, 0, 0);
            }
        }
    };

    auto fixup = [&]() {                                // zero clamp-loaded halo
#pragma unroll
        for (int pass = 0; pass < 2; ++pass) {
            const int gidx = (tid >> 3) + 32 * pass, c = tid & 7;
            int sid = -1;
            if (gidx < 18)      { if (top)   sid = gidx; }             // r=0
            else if (gidx < 36) { if (bot)   sid = 162 + gidx - 18; }  // r=9
            else if (gidx < 46) { if (left)  sid = (gidx - 36) * 18; }        // p=0
            else if (gidx < 56) { if (right) sid = (gidx - 46) * 18 + 17; }   // p=17
            if (sid >= 0) {
                const f16x8 z = {};
                *(f16x8*)(Al + sid * 128 + c * 16)     = z;
                *(f16x8*)(Al + sid * 128 + c * 16 + 8) = z;
            }
        }
    };

    const int l16 = lane & 15, quad = lane >> 4;
    const int mg = w & 1, ng = w >> 1;
    const int r0 = mg * 4;                       // first of 4 rows
    const int n0 = ng * 64;                      // first of 64 oc
    const _Float16* wb = wt + (size_t)(n0 + l16) * 32 + quad * 8;
    const int DR[5] = {1, 0, 2, 1, 1}, DP[5] = {1, 1, 1, 0, 2};

    // A-frag read: site s, chunk c = kc*4+quad, stored at c^(s&7)
    auto lda = [&](int ks, int r) -> f16x8 {
        const int tap = ks >> 2, kc = ks & 3;
        const int s = (DR[tap] + r0 + r) * 18 + DP[tap] + l16;
        const int ch = (kc * 4 + quad) ^ (s & 7);
        return *(const f16x8*)&Al[s * 128 + ch * 8];
    };

    // ---- prologue: stage tile 0
    stage(b0);
    __syncthreads();
    if (edge) { fixup(); __syncthreads(); }

#pragma unroll 1
    for (int t = 0; t < 2; ++t) {
        const int b = b0 + 4 * t;

        f32x4 acc[4][4] = {};
        f16x8 bc[4], bn[4], ac[4], an[4];
#pragma unroll
        for (int nf = 0; nf < 4; ++nf) bc[nf] = *(const f16x8*)(wb + nf * 512);
#pragma unroll
        for (int r = 0; r < 4; ++r) ac[r] = lda(0, r);

#pragma unroll
        for (int ks = 0; ks < 20; ++ks) {
            if (ks < 19) {
#pragma unroll
                for (int nf = 0; nf < 4; ++nf)
                    bn[nf] = *(const f16x8*)(wb + (size_t)(ks + 1) * 4096 + nf * 512);
#pragma unroll
                for (int r = 0; r < 4; ++r) an[r] = lda(ks + 1, r);
            }
            __builtin_amdgcn_s_setprio(1);
#pragma unroll
            for (int r = 0; r < 4; ++r)
#pragma unroll
                for (int nf = 0; nf < 4; ++nf)
                    acc[r][nf] = __builtin_amdgcn_mfma_f32_16x16x32_f16(
                        ac[r], bc[nf], acc[r][nf], 0, 0, 0);
            __builtin_amdgcn_s_setprio(0);
#pragma unroll
            for (int nf = 0; nf < 4; ++nf) bc[nf] = bn[nf];
#pragma unroll
            for (int r = 0; r < 4; ++r) ac[r] = an[r];
        }

        if (t == 0) {
            // all my ds_reads are consumed; ensure retired, then block-wide
            // rendezvous so staging can overwrite Al under the epilogue.
            asm volatile("s_waitcnt lgkmcnt(0)" ::: "memory");
            __builtin_amdgcn_sched_barrier(0);
            __builtin_amdgcn_s_barrier();
            stage(b0 + 4);                       // in-flight across epilogue
        }

        // epilogue (registers/global only — no LDS)
#pragma unroll
        for (int r = 0; r < 4; ++r) {
            const size_t rowb = ((size_t)b * 256 + i0 + r0 + r) * 256 + j0;
#pragma unroll
            for (int nf = 0; nf < 4; ++nf) {
                const float bv = bias[n0 + nf * 16 + l16];
#pragma unroll
                for (int vi = 0; vi < 4; ++vi)
                    outp[(rowb + quad * 4 + vi) * 128 + n0 + nf * 16 + l16] =
                        (_Float16)fmaxf(acc[r][nf][vi] + bv, 0.f);
            }
        }

        if (t == 0) {
            asm volatile("s_waitcnt vmcnt(0)" ::: "memory");
            __builtin_amdgcn_sched_barrier(0);
            __builtin_amdgcn_s_barrier();        // staging landed in all waves
            if (edge) { fixup(); __syncthreads(); }
        }
    }
}

// ---------------- L4: 128 -> 6 (pad 16), gmid-style tiles + gload_lds -------
// 8-row x 16-px tile (grid 16x32x8). Staging/fixup identical to round-9 gmid.
// M = 128 px (8 frags of 16), N = 16 (6 oc + pad), K = 640.
// Wave w computes M-frags {2w, 2w+1} (rows 2w, 2w+1). 40 MFMA/wave.
// 1-deep prefetch of (bf, af0, af1) across the k-loop.
__global__ __launch_bounds__(256, 3) void g4(
    const _Float16* __restrict__ in, const float* __restrict__ bias,
    float* __restrict__ outp)
{
    __shared__ __align__(16) _Float16 Al[180 * 128];    // 46080 B, linear
    const int tid = threadIdx.x;
    const int lane = tid & 63, w = tid >> 6;
    const int j0 = blockIdx.x * 16, i0 = blockIdx.y * 8, b = blockIdx.z;
    const bool top = (blockIdx.y == 0), bot = (blockIdx.y == 31);
    const bool left = (blockIdx.x == 0), right = (blockIdx.x == 15);

    {
        const int pxl = lane & 15;
#pragma unroll
        for (int k = 0; k < 12; ++k) {
            const int m = w + 4 * k;
            if (m < 45) {
                const int s = 4 * m + (lane >> 4);
                const int r = (s * 114) >> 11;          // s/18 for s<288
                const int p = s - 18 * r;
                int gi = i0 - 1 + r; gi = gi < 0 ? 0 : (gi > 255 ? 255 : gi);
                int gj = j0 - 1 + p; gj = gj < 0 ? 0 : (gj > 255 ? 255 : gj);
                const _Float16* src = in + (((size_t)(b * 256 + gi)) * 256 + gj) * 128
                                         + ((pxl ^ (s & 7)) << 3);
                __builtin_amdgcn_global_load_lds(
                    (const __attribute__((address_space(1))) void*)src,
                    (__attribute__((address_space(3))) void*)(Al + m * 512),
                    16, 0, 0);
            }
        }
    }
    __syncthreads();
    if (top | bot | left | right) {                     // zero clamp-loaded halo
#pragma unroll
        for (int pass = 0; pass < 2; ++pass) {
            const int gidx = (tid >> 3) + 32 * pass, c = tid & 7;
            int sid = -1;
            if (gidx < 18)      { if (top)   sid = gidx; }             // r=0
            else if (gidx < 36) { if (bot)   sid = 162 + gidx - 18; }  // r=9
            else if (gidx < 46) { if (left)  sid = (gidx - 36) * 18; }        // p=0
            else if (gidx < 56) { if (right) sid = (gidx - 46) * 18 + 17; }   // p=17
            if (sid >= 0) {
                const f16x8 z = {};
                *(f16x8*)(Al + sid * 128 + c * 16)     = z;
                *(f16x8*)(Al + sid * 128 + c * 16 + 8) = z;
            }
        }
        __syncthreads();
    }

    const int l16 = lane & 15, quad = lane >> 4;
    const int DR[5] = {1, 0, 2, 1, 1}, DP[5] = {1, 1, 1, 0, 2};

    auto lda = [&](int ks, int row) -> f16x8 {
        const int tap = ks >> 2, kc = ks & 3;
        const int s = (DR[tap] + row) * 18 + DP[tap] + l16;
        const int ch = (kc * 4 + quad) ^ (s & 7);
        return *(const f16x8*)&Al[s * 128 + ch * 8];
    };
    auto ldb = [&](int ks) -> f16x8 {
        const int tap = ks >> 2, kc = ks & 3;
        return *(const f16x8*)&W4g[(size_t)(tap * 16 + l16) * 128 + kc * 32 + quad * 8];
    };

    f32x4 acc[2] = {};
    f16x8 bfc = ldb(0), bfn;
    f16x8 afc0 = lda(0, 2 * w), afc1 = lda(0, 2 * w + 1), afn0, afn1;
#pragma unroll
    for (int ks = 0; ks < 20; ++ks) {
        if (ks < 19) {
            bfn  = ldb(ks + 1);
            afn0 = lda(ks + 1, 2 * w);
            afn1 = lda(ks + 1, 2 * w + 1);
        }
        __builtin_amdgcn_s_setprio(1);
        acc[0] = __builtin_amdgcn_mfma_f32_16x16x32_f16(afc0, bfc, acc[0], 0, 0, 0);
        acc[1] = __builtin_amdgcn_mfma_f32_16x16x32_f16(afc1, bfc, acc[1], 0, 0, 0);
        __builtin_amdgcn_s_setprio(0);
        bfc = bfn; afc0 = afn0; afc1 = afn1;
    }

    if (l16 < 6) {
        const float bb = bias[l16];
#pragma unroll
        for (int f = 0; f < 2; ++f) {
            const int i = i0 + 2 * w + f;
#pragma unroll
            for (int vi = 0; vi < 4; ++vi) {
                int jj = j0 + quad * 4 + vi;
                outp[(((size_t)b * 6 + l16) << 16) + i * 256 + jj] = acc[f][vi] + bb;
            }
        }
    }
}

extern "C" void kernel_launch(void* const* d_in, const int* in_sizes, int n_in,
                              void* d_out, int out_size, void* d_ws, size_t ws_size,
                              hipStream_t stream) {
    const float* x  = (const float*)d_in[0];
    const float* w1 = (const float*)d_in[1];
    const float* b1 = (const float*)d_in[2];
    const float* w2 = (const float*)d_in[3];
    const float* b2 = (const float*)d_in[4];
    const float* w3 = (const float*)d_in[5];
    const float* b3 = (const float*)d_in[6];
    const float* w4 = (const float*)d_in[7];
    const float* b4 = (const float*)d_in[8];
    float* out = (float*)d_out;

    const size_t act = (size_t)BB * HH * WW * 128;
    _Float16* A1 = (_Float16*)d_ws;
    _Float16* A2 = A1 + act;                    // exactly 268435456 B total

    prep<<<696, 256, 0, stream>>>(w1, w2, w3, w4);
    dim3 blk(256, 1, 1);
    dim3 gm(16, 32, 8);                         // 16-px x 8-row tiles
    g1<<<gm, blk, 0, stream>>>(x, b1, A1);
    gmid<2><<<dim3(16, 32, 4), blk, 0, stream>>>(A1, b2, A2);
    gmid<3><<<dim3(16, 32, 4), blk, 0, stream>>>(A2, b3, A1);
    g4<<<gm, blk, 0, stream>>>(A1, b4, out);
}

// Round 10
// 377.931 us; speedup vs baseline: 3.8004x; 2.7120x over previous
//
#include <hip/hip_runtime.h>

// 4-layer 5-point cross-stencil CNN, implicit GEMM on MFMA (MI355X gfx950).
// Round 15: r11 base; gmid k-loop -> ring-3 B / ring-2 A at launch_bounds(256,2).
//   r12-r14 post-mortem: at bounds(256,3) the shape has zero VGPR headroom
//   (84 arch + 64 AGPR ~= 170 cap); every added live state spilled to scratch
//   (r7: FETCH 175MB; r13: 645MB; r14: 508MB + 606MB WRITE). The drain-overlap
//   mechanism never got tested -- the register budget was the wall.
//   This round changes the budget, not the structure: gmid alone drops to
//   2 blocks/CU (256-VGPR cap, spill impossible at ~174 used) and re-grafts
//   r7's ring-3 B prefetch (2 iters = 160cy in-wave cover vs ~200-400cy L2
//   latency) + ring-2 A. k-loop otherwise identical; staging/swizzle/lda/
//   fixup/epilogue byte-identical to r11. g1/g4/prep byte-identical to r11.
//   Tripwire: gmid FETCH>90MB or WRITE>140MB = spill -> revert to r11.
// MFMA 16x16x32_f16 layouts (verified round 3):
//   A[m=lane&15][k=quad*8+j], B[n=lane&15][k=quad*8+j], C: col=lane&15,
//   row=quad*4+reg.   Taps: 0=c,1=up,2=down,3=left,4=right.

#define BB   8
#define HH   256
#define WW   256

typedef _Float16 f16x8 __attribute__((ext_vector_type(8)));
typedef float    f32x4 __attribute__((ext_vector_type(4)));

// K-major fp16 weight tables (rewritten every launch by prep).
__device__ _Float16 W1g[128 * 32];       // [oc][k], k=tap*6+ic, 30..31 = 0
__device__ _Float16 W2g[20 * 128 * 32];  // [ks=tap*4+kc][oc][icb]
__device__ _Float16 W3g[20 * 128 * 32];
__device__ _Float16 W4g[5 * 16 * 128];   // [tap][oc(pad16)][ic]

__global__ void prep(const float* __restrict__ w1, const float* __restrict__ w2,
                     const float* __restrict__ w3, const float* __restrict__ w4)
{
    int idx = blockIdx.x * 256 + threadIdx.x;
    if (idx < 81920) {                                  // W2g
        int icb = idx & 31, oc = (idx >> 5) & 127, ks = idx >> 12;
        int tap = ks >> 2, ic = (ks & 3) * 32 + icb;
        W2g[idx] = (_Float16)w2[(oc * 128 + ic) * 5 + tap];
    } else if (idx < 163840) {                          // W3g
        int k = idx - 81920;
        int icb = k & 31, oc = (k >> 5) & 127, ks = k >> 12;
        int tap = ks >> 2, ic = (ks & 3) * 32 + icb;
        W3g[k] = (_Float16)w3[(oc * 128 + ic) * 5 + tap];
    } else if (idx < 174080) {                          // W4g
        int k = idx - 163840;
        int t = k / 2048, oc = (k >> 7) & 15, ic = k & 127;
        W4g[k] = (_Float16)((oc < 6) ? w4[(oc * 128 + ic) * 5 + t] : 0.f);
    } else if (idx < 178176) {                          // W1g
        int k = idx - 174080;
        int kk = k & 31, oc = k >> 5;
        float v = 0.f;
        if (kk < 30) {
            int tap = (kk * 43) >> 8;                   // kk/6 for kk<30
            int ic = kk - 6 * tap;
            v = w1[(oc * 6 + ic) * 5 + tap];
        }
        W1g[k] = (_Float16)v;
    }
}

// ---------------- L1: MFMA, K=32 (tap*6+ic, padded). NCHW fp32 -> NHWC fp16.
// Staging planes k=2*it+HALF: HALF wave-uniform -> tap/ic/di/dj compile-time.
template<int HALF, bool EDGE>
__device__ __forceinline__ void g1_stage(const float* __restrict__ xb,
                                         _Float16* __restrict__ Ap,
                                         int px, int gi0, int gj0)
{
#pragma unroll
    for (int it = 0; it < 15; ++it) {
        const int k = 2 * it + HALF;                    // compile-time
        const int tap = k / 6, ic = k - 6 * tap;
        const int DI = (tap == 1) ? -1 : ((tap == 2) ? 1 : 0);
        const int DJ = (tap == 3) ? -1 : ((tap == 4) ? 1 : 0);
        const float* sp = xb + ic * 65536 + DI * 256 + DJ;
        float v;
        if (EDGE) {
            const int gi = gi0 + DI, gj = gj0 + DJ;
            v = ((unsigned)gi < 256u && (unsigned)gj < 256u) ? *sp : 0.f;
        } else {
            v = *sp;
        }
        Ap[px * 40 + k] = (_Float16)v;
    }
    Ap[px * 40 + 30 + HALF] = (_Float16)0.f;            // K-pad 30/31
}

__global__ __launch_bounds__(256, 3) void g1(
    const float* __restrict__ x, const float* __restrict__ bias,
    _Float16* __restrict__ outp)
{
    __shared__ _Float16 Ap[128 * 40];
    const int tid = threadIdx.x;
    const int j0 = blockIdx.x * 16, i0 = blockIdx.y * 8, b = blockIdx.z;
    const int px = tid & 127, half = tid >> 7;
    const int pr = px >> 4, pp = px & 15;
    const bool edge = (blockIdx.y == 0) | (blockIdx.y == 31) |
                      (blockIdx.x == 0) | (blockIdx.x == 15);
    const int gi0 = i0 + pr, gj0 = j0 + pp;
    const float* xb = x + (size_t)b * 6 * 65536 + gi0 * 256 + gj0;

    if (edge) {
        if (half == 0) g1_stage<0, true >(xb, Ap, px, gi0, gj0);
        else           g1_stage<1, true >(xb, Ap, px, gi0, gj0);
    } else {
        if (half == 0) g1_stage<0, false>(xb, Ap, px, gi0, gj0);
        else           g1_stage<1, false>(xb, Ap, px, gi0, gj0);
    }
    __syncthreads();

    const int lane = tid & 63, w = tid >> 6, l16 = lane & 15, quad = lane >> 4;
    f32x4 acc[2][8] = {};
    f16x8 a0 = *(const f16x8*)&Ap[((2 * w + 0) * 16 + l16) * 40 + quad * 8];
    f16x8 a1 = *(const f16x8*)&Ap[((2 * w + 1) * 16 + l16) * 40 + quad * 8];
#pragma unroll
    for (int nf = 0; nf < 8; ++nf) {
        f16x8 bf = *(const f16x8*)&W1g[(nf * 16 + l16) * 32 + quad * 8];
        acc[0][nf] = __builtin_amdgcn_mfma_f32_16x16x32_f16(a0, bf, acc[0][nf], 0, 0, 0);
        acc[1][nf] = __builtin_amdgcn_mfma_f32_16x16x32_f16(a1, bf, acc[1][nf], 0, 0, 0);
    }
#pragma unroll
    for (int mf = 0; mf < 2; ++mf) {
        const size_t rowb = ((size_t)b * 256 + i0 + 2 * w + mf) * 256 + j0;
#pragma unroll
        for (int nf = 0; nf < 8; ++nf) {
            const float bv = bias[nf * 16 + l16];
#pragma unroll
            for (int r = 0; r < 4; ++r)
                outp[(rowb + quad * 4 + r) * 128 + nf * 16 + l16] =
                    (_Float16)fmaxf(acc[mf][nf][r] + bv, 0.f);
        }
    }
}

// ---------------- middle layers: M=128 (8 rows x 16 px), N=128, K=640 -------
// 2x2 wave grid: wave(mg,ng) owns rows r0..r0+3 and oc n0..n0+63.
// Staging: 45 global_load_lds(16B) wave-instrs into linear LDS [180][128],
// chunk XOR-swizzled via source address (r9-proven).
// k-loop: ring-3 B (2 iters ahead, 160cy cover vs ~200-400cy L2 latency),
// ring-2 A (1 iter ahead). 2 blocks/CU via launch_bounds(256,2): ~174 regs
// used of 256 cap -> no spill (the r7/r13/r14 failure mode).
template<int LAYER>
__global__ __launch_bounds__(256, 2) void gmid(
    const _Float16* __restrict__ in, const float* __restrict__ bias,
    _Float16* __restrict__ outp)
{
    const _Float16* wt = (LAYER == 2) ? W2g : W3g;
    __shared__ __align__(16) _Float16 Al[180 * 128];    // 46080 B, linear
    const int tid = threadIdx.x;
    const int lane = tid & 63, w = tid >> 6;
    const int j0 = blockIdx.x * 16, i0 = blockIdx.y * 8, b = blockIdx.z;
    const bool top = (blockIdx.y == 0), bot = (blockIdx.y == 31);
    const bool left = (blockIdx.x == 0), right = (blockIdx.x == 15);

    // ---- staging: instr m stages sites 4m..4m+3 (1024 B linear LDS).
    // lane l -> site s=4m+(l>>4); stored chunk (l&15) := global chunk
    // (l&15)^(s&7)  (XOR swizzle folded into the per-lane source address).
    {
        const int pxl = lane & 15;
#pragma unroll
        for (int k = 0; k < 12; ++k) {
            const int m = w + 4 * k;
            if (m < 45) {
                const int s = 4 * m + (lane >> 4);
                const int r = (s * 114) >> 11;          // s/18 for s<288
                const int p = s - 18 * r;
                int gi = i0 - 1 + r; gi = gi < 0 ? 0 : (gi > 255 ? 255 : gi);
                int gj = j0 - 1 + p; gj = gj < 0 ? 0 : (gj > 255 ? 255 : gj);
                const _Float16* src = in + (((size_t)(b * 256 + gi)) * 256 + gj) * 128
                                         + ((pxl ^ (s & 7)) << 3);
                __builtin_amdgcn_global_load_lds(
                    (const __attribute__((address_space(1))) void*)src,
                    (__attribute__((address_space(3))) void*)(Al + m * 512),
                    16, 0, 0);
            }
        }
    }
    __syncthreads();
    if (top | bot | left | right) {                     // zero clamp-loaded halo
        // 56 site-groups x 8 chunks = 448 slots; 256 threads x 2 passes.
#pragma unroll
        for (int pass = 0; pass < 2; ++pass) {
            const int gidx = (tid >> 3) + 32 * pass, c = tid & 7;
            int sid = -1;
            if (gidx < 18)      { if (top)   sid = gidx; }             // r=0
            else if (gidx < 36) { if (bot)   sid = 162 + gidx - 18; }  // r=9
            else if (gidx < 46) { if (left)  sid = (gidx - 36) * 18; }        // p=0
            else if (gidx < 56) { if (right) sid = (gidx - 46) * 18 + 17; }   // p=17
            if (sid >= 0) {
                const f16x8 z = {};
                *(f16x8*)(Al + sid * 128 + c * 16)     = z;
                *(f16x8*)(Al + sid * 128 + c * 16 + 8) = z;
            }
        }
        __syncthreads();
    }

    const int l16 = lane & 15, quad = lane >> 4;
    const int mg = w & 1, ng = w >> 1;
    const int r0 = mg * 4;                       // first of 4 rows
    const int n0 = ng * 64;                      // first of 64 oc

    const _Float16* wb = wt + (size_t)(n0 + l16) * 32 + quad * 8;
    // B frag (ks, nf) at wb + ks*4096 + nf*512

    f32x4 acc[4][4] = {};
    const int DR[5] = {1, 0, 2, 1, 1}, DP[5] = {1, 1, 1, 0, 2};

    // A-frag read: site s, chunk c = kc*4+quad, stored at c^(s&7)
    auto lda = [&](int ks, int r) -> f16x8 {
        const int tap = ks >> 2, kc = ks & 3;
        const int s = (DR[tap] + r0 + r) * 18 + DP[tap] + l16;
        const int ch = (kc * 4 + quad) ^ (s & 7);
        return *(const f16x8*)&Al[s * 128 + ch * 8];
    };

    f16x8 br[3][4], ar[2][4];
    // preload: B for ks=0,1 ; A for ks=0
#pragma unroll
    for (int pk = 0; pk < 2; ++pk)
#pragma unroll
        for (int nf = 0; nf < 4; ++nf)
            br[pk][nf] = *(const f16x8*)(wb + (size_t)pk * 4096 + nf * 512);
#pragma unroll
    for (int r = 0; r < 4; ++r) ar[0][r] = lda(0, r);

#pragma unroll
    for (int ks = 0; ks < 20; ++ks) {
        if (ks + 2 < 20) {                       // B two iterations ahead
#pragma unroll
            for (int nf = 0; nf < 4; ++nf)
                br[(ks + 2) % 3][nf] =
                    *(const f16x8*)(wb + (size_t)(ks + 2) * 4096 + nf * 512);
        }
        if (ks + 1 < 20) {                       // A one iteration ahead
#pragma unroll
            for (int r = 0; r < 4; ++r) ar[(ks + 1) & 1][r] = lda(ks + 1, r);
        }
        __builtin_amdgcn_s_setprio(1);
#pragma unroll
        for (int r = 0; r < 4; ++r)
#pragma unroll
            for (int nf = 0; nf < 4; ++nf)
                acc[r][nf] = __builtin_amdgcn_mfma_f32_16x16x32_f16(
                    ar[ks & 1][r], br[ks % 3][nf], acc[r][nf], 0, 0, 0);
        __builtin_amdgcn_s_setprio(0);
    }

#pragma unroll
    for (int r = 0; r < 4; ++r) {
        const size_t rowb = ((size_t)b * 256 + i0 + r0 + r) * 256 + j0;
#pragma unroll
        for (int nf = 0; nf < 4; ++nf) {
            const float bv = bias[n0 + nf * 16 + l16];
#pragma unroll
            for (int vi = 0; vi < 4; ++vi)
                outp[(rowb + quad * 4 + vi) * 128 + n0 + nf * 16 + l16] =
                    (_Float16)fmaxf(acc[r][nf][vi] + bv, 0.f);
        }
    }
}

// ---------------- L4: 128 -> 6 (pad 16), gmid-style tiles + gload_lds -------
// 8-row x 16-px tile (grid 16x32x8). Staging/fixup identical to round-9 gmid.
// M = 128 px (8 frags of 16), N = 16 (6 oc + pad), K = 640.
// Wave w computes M-frags {2w, 2w+1} (rows 2w, 2w+1). 40 MFMA/wave.
// 1-deep prefetch of (bf, af0, af1) across the k-loop.
__global__ __launch_bounds__(256, 3) void g4(
    const _Float16* __restrict__ in, const float* __restrict__ bias,
    float* __restrict__ outp)
{
    __shared__ __align__(16) _Float16 Al[180 * 128];    // 46080 B, linear
    const int tid = threadIdx.x;
    const int lane = tid & 63, w = tid >> 6;
    const int j0 = blockIdx.x * 16, i0 = blockIdx.y * 8, b = blockIdx.z;
    const bool top = (blockIdx.y == 0), bot = (blockIdx.y == 31);
    const bool left = (blockIdx.x == 0), right = (blockIdx.x == 15);

    {
        const int pxl = lane & 15;
#pragma unroll
        for (int k = 0; k < 12; ++k) {
            const int m = w + 4 * k;
            if (m < 45) {
                const int s = 4 * m + (lane >> 4);
                const int r = (s * 114) >> 11;          // s/18 for s<288
                const int p = s - 18 * r;
                int gi = i0 - 1 + r; gi = gi < 0 ? 0 : (gi > 255 ? 255 : gi);
                int gj = j0 - 1 + p; gj = gj < 0 ? 0 : (gj > 255 ? 255 : gj);
                const _Float16* src = in + (((size_t)(b * 256 + gi)) * 256 + gj) * 128
                                         + ((pxl ^ (s & 7)) << 3);
                __builtin_amdgcn_global_load_lds(
                    (const __attribute__((address_space(1))) void*)src,
                    (__attribute__((address_space(3))) void*)(Al + m * 512),
                    16, 0, 0);
            }
        }
    }
    __syncthreads();
    if (top | bot | left | right) {                     // zero clamp-loaded halo
#pragma unroll
        for (int pass = 0; pass < 2; ++pass) {
            const int gidx = (tid >> 3) + 32 * pass, c = tid & 7;
            int sid = -1;
            if (gidx < 18)      { if (top)   sid = gidx; }             // r=0
            else if (gidx < 36) { if (bot)   sid = 162 + gidx - 18; }  // r=9
            else if (gidx < 46) { if (left)  sid = (gidx - 36) * 18; }        // p=0
            else if (gidx < 56) { if (right) sid = (gidx - 46) * 18 + 17; }   // p=17
            if (sid >= 0) {
                const f16x8 z = {};
                *(f16x8*)(Al + sid * 128 + c * 16)     = z;
                *(f16x8*)(Al + sid * 128 + c * 16 + 8) = z;
            }
        }
        __syncthreads();
    }

    const int l16 = lane & 15, quad = lane >> 4;
    const int DR[5] = {1, 0, 2, 1, 1}, DP[5] = {1, 1, 1, 0, 2};

    auto lda = [&](int ks, int row) -> f16x8 {
        const int tap = ks >> 2, kc = ks & 3;
        const int s = (DR[tap] + row) * 18 + DP[tap] + l16;
        const int ch = (kc * 4 + quad) ^ (s & 7);
        return *(const f16x8*)&Al[s * 128 + ch * 8];
    };
    auto ldb = [&](int ks) -> f16x8 {
        const int tap = ks >> 2, kc = ks & 3;
        return *(const f16x8*)&W4g[(size_t)(tap * 16 + l16) * 128 + kc * 32 + quad * 8];
    };

    f32x4 acc[2] = {};
    f16x8 bfc = ldb(0), bfn;
    f16x8 afc0 = lda(0, 2 * w), afc1 = lda(0, 2 * w + 1), afn0, afn1;
#pragma unroll
    for (int ks = 0; ks < 20; ++ks) {
        if (ks < 19) {
            bfn  = ldb(ks + 1);
            afn0 = lda(ks + 1, 2 * w);
            afn1 = lda(ks + 1, 2 * w + 1);
        }
        __builtin_amdgcn_s_setprio(1);
        acc[0] = __builtin_amdgcn_mfma_f32_16x16x32_f16(afc0, bfc, acc[0], 0, 0, 0);
        acc[1] = __builtin_amdgcn_mfma_f32_16x16x32_f16(afc1, bfc, acc[1], 0, 0, 0);
        __builtin_amdgcn_s_setprio(0);
        bfc = bfn; afc0 = afn0; afc1 = afn1;
    }

    if (l16 < 6) {
        const float bb = bias[l16];
#pragma unroll
        for (int f = 0; f < 2; ++f) {
            const int i = i0 + 2 * w + f;
#pragma unroll
            for (int vi = 0; vi < 4; ++vi) {
                int jj = j0 + quad * 4 + vi;
                outp[(((size_t)b * 6 + l16) << 16) + i * 256 + jj] = acc[f][vi] + bb;
            }
        }
    }
}

extern "C" void kernel_launch(void* const* d_in, const int* in_sizes, int n_in,
                              void* d_out, int out_size, void* d_ws, size_t ws_size,
                              hipStream_t stream) {
    const float* x  = (const float*)d_in[0];
    const float* w1 = (const float*)d_in[1];
    const float* b1 = (const float*)d_in[2];
    const float* w2 = (const float*)d_in[3];
    const float* b2 = (const float*)d_in[4];
    const float* w3 = (const float*)d_in[5];
    const float* b3 = (const float*)d_in[6];
    const float* w4 = (const float*)d_in[7];
    const float* b4 = (const float*)d_in[8];
    float* out = (float*)d_out;

    const size_t act = (size_t)BB * HH * WW * 128;
    _Float16* A1 = (_Float16*)d_ws;
    _Float16* A2 = A1 + act;                    // exactly 268435456 B total

    prep<<<696, 256, 0, stream>>>(w1, w2, w3, w4);
    dim3 blk(256, 1, 1);
    dim3 gm(16, 32, 8);                         // 16-px x 8-row tiles
    g1<<<gm, blk, 0, stream>>>(x, b1, A1);
    gmid<2><<<gm, blk, 0, stream>>>(A1, b2, A2);
    gmid<3><<<gm, blk, 0, stream>>>(A2, b3, A1);
    g4<<<gm, blk, 0, stream>>>(A1, b4, out);
}